// Round 1
// baseline (346.255 us; speedup 1.0000x reference)
//
#include <hip/hip_runtime.h>

// ---------------- problem constants ----------------
#define NNODES 200
#define FEATX  2600      // 50*52
#define FEAT   2800      // FEATX + NNODES
#define KPAD   2816      // 44 * 64
#define NCH    44
#define N1     128

typedef _Float16 f16;
typedef _Float16 f16x8 __attribute__((ext_vector_type(8)));
typedef float    f32x4 __attribute__((ext_vector_type(4)));

// ---------------- workspace byte offsets ----------------
#define W1T_OFF   0u          // 44 * 16384 = 720896  (swizzled fp16 W1^T chunks)
#define W2T_OFF   720896u     // 32768 (swizzled fp16 W2^T)
#define W3T_OFF   753664u     // 16384 (swizzled fp16 W3^T)
#define WG_OFF    770048u     // 200*128*4 = 102400 (fp32 Wg' accumulator)
#define B1P_OFF   872448u     // 512   (fp32 folded bias b1')
#define HW_OFF    872960u     // 16    (fp32 hw_val[3])
#define WE_OFF    874816u     // 3200  (fp32 per-edge weight)

__device__ __forceinline__ void gl_lds16(const void* g, void* l) {
  __builtin_amdgcn_global_load_lds(
      (const __attribute__((address_space(1))) unsigned int*)g,
      (__attribute__((address_space(3))) unsigned int*)l, 16, 0, 0);
}

// ============ P0a: degrees, norms, hw_val, edge weights, b1', zero Wg ============
__global__ void p0a(const int* __restrict__ esrc, const int* __restrict__ edst,
                    const float* __restrict__ emb, const float* __restrict__ gcw,
                    const float* __restrict__ gcb, const float* __restrict__ W1,
                    const float* __restrict__ b1, char* __restrict__ ws) {
  __shared__ float dg[2][NNODES];
  const int tid = threadIdx.x;  // 256
  for (int i = tid; i < 2 * NNODES; i += 256) ((float*)dg)[i] = 0.f;
  __syncthreads();
  for (int e = tid; e < 800; e += 256) {
    atomicAdd(&dg[0][esrc[e]], 1.f);
    atomicAdd(&dg[1][edst[e]], 1.f);
  }
  __syncthreads();
  for (int i = tid; i < 2 * NNODES; i += 256) {
    float* p = (float*)dg + i;
    *p = 1.f / sqrtf(fmaxf(*p, 1.f));
  }
  if (tid < 3) {
    float s = 0.f;
    for (int q = 0; q < 5; ++q) s += emb[tid * 5 + q] * gcw[q];
    ((float*)(ws + HW_OFF))[tid] = s;
  }
  __syncthreads();
  float* we = (float*)(ws + WE_OFF);
  for (int e = tid; e < 800; e += 256)
    we[e] = dg[0][esrc[e]] * dg[1][edst[e]];
  if (tid < 128) {
    float s = 0.f;
    for (int d = 0; d < NNODES; ++d) s += W1[(FEATX + d) * N1 + tid];
    ((float*)(ws + B1P_OFF))[tid] = b1[tid] + gcb[0] * s;
  }
  float* wg = (float*)(ws + WG_OFF);
  for (int i = tid; i < NNODES * N1; i += 256) wg[i] = 0.f;
}

// ============ P0edge: Wg'[n,j] += we[e] * W1g[dst,j] for src=n ============
__global__ void p0edge(const int* __restrict__ esrc, const int* __restrict__ edst,
                       const float* __restrict__ W1, char* __restrict__ ws) {
  const float* we = (const float*)(ws + WE_OFF);
  float* wg = (float*)(ws + WG_OFF);
  const int j = threadIdx.x & 127;
  const int h = threadIdx.x >> 7;               // 0..1
  const int e0 = blockIdx.x * 25;               // 32 blocks * 25 = 800
  for (int e = e0 + h; e < e0 + 25; e += 2) {
    const int s = esrc[e], d = edst[e];
    atomicAdd(&wg[s * N1 + j], we[e] * W1[(FEATX + d) * N1 + j]);
  }
}

// ============ P0pack: swizzled fp16 W1^T chunks (+g tail, zero pad), W2^T, W3^T ====
__global__ void p0pack(const float* __restrict__ W1, const float* __restrict__ W2,
                       const float* __restrict__ W3, char* __restrict__ ws) {
  const int bid = blockIdx.x, tid = threadIdx.x;  // 46 blocks x 256
  if (bid < NCH) {
    char* dst = ws + W1T_OFF + bid * 16384;
    const float* wg = (const float*)(ws + WG_OFF);
    const int c = tid & 127, kh = tid >> 7;
    for (int kk = kh; kk < 64; kk += 2) {
      const int k = bid * 64 + kk;
      float v;
      if (k < FEATX) v = W1[k * N1 + c];
      else if (k < FEAT) v = wg[(k - FEATX) * N1 + c];
      else v = 0.f;
      const int off = (c * 128 + kk * 2) ^ ((c & 7) << 4);
      *(f16*)(dst + off) = (f16)v;
    }
  } else if (bid == NCH) {
    char* dst = ws + W2T_OFF;
    const int c = tid & 127, kh = tid >> 7;
    for (int k = kh; k < 128; k += 2) {
      const float v = W2[k * 128 + c];
      const int off = (c * 256 + k * 2) ^ ((c & 7) << 4);
      *(f16*)(dst + off) = (f16)v;
    }
  } else {
    char* dst = ws + W3T_OFF;
    const int c = tid & 63, kh = tid >> 6;
    for (int k = kh; k < 128; k += 4) {
      const float v = W3[k * 64 + c];
      const int off = (c * 256 + k * 2) ^ ((c & 7) << 4);
      *(f16*)(dst + off) = (f16)v;
    }
  }
}

// ============ fused main: GEMM1(2816) + softplus + GEMM2 + softplus + GEMM3
//              + tanhshrink + GEMM4 + sigmoid ============
__global__ __launch_bounds__(512, 2)
void fused_main(const float* __restrict__ x, const int* __restrict__ apps,
                const char* __restrict__ ws, const float* __restrict__ b2,
                const float* __restrict__ b3, const float* __restrict__ W4,
                const float* __restrict__ b4, float* __restrict__ out) {
  __shared__ __align__(16) char lds[147456];
  char*  sA    = lds;                 // 2 x 8192   A chunk double buffer
  char*  sB    = lds + 16384;         // 2 x 16384  B chunk double buffer
  char*  sW23  = lds + 49152;         // 49152      W2^T (32768) + W3^T (16384)
  char*  sAct1 = lds + 98304;         // 16384      a1 fp16 [64][128]
  char*  sAct2 = lds + 114688;        // 16384      a2 fp16 [64][128]
  float* sAct3 = (float*)(lds + 131072); // 16384   a3 fp32 [64][64]

  const int tid  = threadIdx.x;
  const int lane = tid & 63;
  const int w    = tid >> 6;          // wave 0..7
  const int lrow = lane & 15;
  const int lk   = lane >> 4;         // 0..3
  const int wr   = w >> 1;            // row tile 0..3 (16 rows each)
  const int wc   = w & 1;             // col tile 0..1 (64 cols each)
  const int blk  = blockIdx.x;

  const float* hwv = (const float*)(ws + HW_OFF);
  const float hw0 = hwv[0], hw1 = hwv[1], hw2 = hwv[2];

  // staging mapping: each thread owns (row sr, 8-wide k slice sq)
  const int sr = tid >> 3;            // 0..63
  const int sq = tid & 7;             // 0..7
  const float* xrow = x + (size_t)(blk * 64 + sr) * FEATX;
  const int*   arow = apps + (size_t)(blk * 64 + sr) * NNODES;

  // fragment LDS byte offsets (BK=64 chunk, row stride 128B, XOR swizzle)
  int aoff[2], boff[2][4];
#pragma unroll
  for (int ks = 0; ks < 2; ++ks) {
    const int arow_ = wr * 16 + lrow;
    aoff[ks] = ((arow_ * 128 + ks * 64 + lk * 16) ^ ((lrow & 7) << 4));
#pragma unroll
    for (int f = 0; f < 4; ++f) {
      const int c = wc * 64 + f * 16 + lrow;
      boff[ks][f] = ((c * 128 + ks * 64 + lk * 16) ^ ((lrow & 7) << 4));
    }
  }

  const f32x4 zed = {0.f, 0.f, 0.f, 0.f};
  f32x4 acc1[4] = {zed, zed, zed, zed};

  auto loadg = [&](int k) -> uint4 {
    if (k < FEATX) return *(const uint4*)(xrow + k);
    else if (k < FEAT) return *(const uint4*)(arow + (k - FEATX));
    uint4 z; z.x = z.y = z.z = z.w = 0u; return z;
  };
  auto cvt4 = [&](int k, uint4 u, f16* h) {
    if (k < FEATX) {
      h[0] = (f16)__uint_as_float(u.x); h[1] = (f16)__uint_as_float(u.y);
      h[2] = (f16)__uint_as_float(u.z); h[3] = (f16)__uint_as_float(u.w);
    } else if (k < FEAT) {
      h[0] = (f16)(u.x == 0u ? hw0 : (u.x == 1u ? hw1 : hw2));
      h[1] = (f16)(u.y == 0u ? hw0 : (u.y == 1u ? hw1 : hw2));
      h[2] = (f16)(u.z == 0u ? hw0 : (u.z == 1u ? hw1 : hw2));
      h[3] = (f16)(u.w == 0u ? hw0 : (u.w == 1u ? hw2 == hw2 ? hw2 : hw2 : hw2));
      h[3] = (f16)(u.w == 0u ? hw0 : (u.w == 1u ? hw1 : hw2));
    } else {
      h[0] = h[1] = h[2] = h[3] = (f16)0.f;
    }
  };
  auto issueB = [&](int t, int buf) {
    const char* src = ws + W1T_OFF + (size_t)t * 16384;
    char* dst = sB + buf * 16384;
#pragma unroll
    for (int r = 0; r < 2; ++r) {
      const int o = r * 8192 + w * 1024;
      gl_lds16(src + o + lane * 16, dst + o);
    }
  };
  auto writeA = [&](int t, int buf, uint4 u0, uint4 u1) {
    const int k0 = t * 64 + sq * 8;
    union { f16x8 v; f16 h[8]; } u;
    cvt4(k0, u0, u.h);
    cvt4(k0 + 4, u1, u.h + 4);
    *(f16x8*)(sA + (buf << 13) + ((sr * 128 + sq * 16) ^ ((sr & 7) << 4))) = u.v;
  };
  auto computeC1 = [&](int buf) {
    const char* a = sA + (buf << 13);
    const char* b = sB + buf * 16384;
#pragma unroll
    for (int ks = 0; ks < 2; ++ks) {
      const f16x8 af = *(const f16x8*)(a + aoff[ks]);
#pragma unroll
      for (int f = 0; f < 4; ++f) {
        const f16x8 bf = *(const f16x8*)(b + boff[ks][f]);
        acc1[f] = __builtin_amdgcn_mfma_f32_16x16x32_f16(af, bf, acc1[f], 0, 0, 0);
      }
    }
  };

  // -------- pipeline --------
  uint4 uA0, uA1;
  uA0 = loadg(0 * 64 + sq * 8);
  uA1 = loadg(0 * 64 + sq * 8 + 4);
  issueB(0, 0);
  writeA(0, 0, uA0, uA1);
  __syncthreads();

#pragma unroll 2
  for (int t = 0; t < NCH; ++t) {
    const int buf = t & 1;
    if (t + 1 < NCH) {
      uA0 = loadg((t + 1) * 64 + sq * 8);
      uA1 = loadg((t + 1) * 64 + sq * 8 + 4);
      issueB(t + 1, buf ^ 1);
    } else {
      // prefetch W2^T + W3^T (contiguous 48KB in ws) into sW23
#pragma unroll
      for (int r = 0; r < 6; ++r) {
        const int o = r * 8192 + w * 1024;
        gl_lds16(ws + W2T_OFF + o + lane * 16, sW23 + o);
      }
    }
    computeC1(buf);
    if (t + 1 < NCH) writeA(t + 1, buf ^ 1, uA0, uA1);
    __syncthreads();
  }

  // -------- epilogue 1: + b1' , softplus -> sAct1 (fp16, swizzled, stride 256B) ----
  const float* b1p = (const float*)(ws + B1P_OFF);
#pragma unroll
  for (int f = 0; f < 4; ++f) {
    const int col = wc * 64 + f * 16 + lrow;
    const float bb = b1p[col];
#pragma unroll
    for (int r = 0; r < 4; ++r) {
      const int row = wr * 16 + lk * 4 + r;
      float v = acc1[f][r] + bb;
      v = fmaxf(v, 0.f) + log1pf(expf(-fabsf(v)));
      *(f16*)(sAct1 + ((row * 256 + col * 2) ^ ((row & 7) << 4))) = (f16)v;
    }
  }
  __syncthreads();

  // -------- GEMM2: a1[64x128] @ W2[128x128], softplus -> sAct2 --------
  f32x4 acc2[4] = {zed, zed, zed, zed};
#pragma unroll
  for (int ks = 0; ks < 4; ++ks) {
    const int ar = wr * 16 + lrow;
    const f16x8 af = *(const f16x8*)(sAct1 + ((ar * 256 + ks * 64 + lk * 16) ^ ((lrow & 7) << 4)));
#pragma unroll
    for (int f = 0; f < 4; ++f) {
      const int c = wc * 64 + f * 16 + lrow;
      const f16x8 bf = *(const f16x8*)(sW23 + ((c * 256 + ks * 64 + lk * 16) ^ ((lrow & 7) << 4)));
      acc2[f] = __builtin_amdgcn_mfma_f32_16x16x32_f16(af, bf, acc2[f], 0, 0, 0);
    }
  }
#pragma unroll
  for (int f = 0; f < 4; ++f) {
    const int col = wc * 64 + f * 16 + lrow;
    const float bb = b2[col];
#pragma unroll
    for (int r = 0; r < 4; ++r) {
      const int row = wr * 16 + lk * 4 + r;
      float v = acc2[f][r] + bb;
      v = fmaxf(v, 0.f) + log1pf(expf(-fabsf(v)));
      *(f16*)(sAct2 + ((row * 256 + col * 2) ^ ((row & 7) << 4))) = (f16)v;
    }
  }
  __syncthreads();

  // -------- GEMM3: a2[64x128] @ W3[128x64], tanhshrink -> sAct3 (fp32) --------
  f32x4 acc3[2] = {zed, zed};
  const char* w3 = sW23 + 32768;
#pragma unroll
  for (int ks = 0; ks < 4; ++ks) {
    const int ar = wr * 16 + lrow;
    const f16x8 af = *(const f16x8*)(sAct2 + ((ar * 256 + ks * 64 + lk * 16) ^ ((lrow & 7) << 4)));
#pragma unroll
    for (int f = 0; f < 2; ++f) {
      const int c = wc * 32 + f * 16 + lrow;
      const f16x8 bf = *(const f16x8*)(w3 + ((c * 256 + ks * 64 + lk * 16) ^ ((lrow & 7) << 4)));
      acc3[f] = __builtin_amdgcn_mfma_f32_16x16x32_f16(af, bf, acc3[f], 0, 0, 0);
    }
  }
#pragma unroll
  for (int f = 0; f < 2; ++f) {
    const int col = wc * 32 + f * 16 + lrow;
    const float bb = b3[col];
#pragma unroll
    for (int r = 0; r < 4; ++r) {
      const int row = wr * 16 + lk * 4 + r;
      const float z = acc3[f][r] + bb;
      sAct3[row * 64 + col] = z - tanhf(z);
    }
  }
  __syncthreads();

  // -------- GEMM4 (vector fp32): a3[64x64] @ W4[64x2] + b4, sigmoid --------
  if (tid < 128) {
    const int row = tid >> 1, j = tid & 1;
    float a4 = b4[j];
#pragma unroll 8
    for (int k = 0; k < 64; ++k)
      a4 += sAct3[row * 64 + k] * W4[k * 2 + j];
    out[(size_t)(blk * 64 + row) * 2 + j] = 1.f / (1.f + expf(-a4));
  }
}

// ---------------- launch ----------------
extern "C" void kernel_launch(void* const* d_in, const int* in_sizes, int n_in,
                              void* d_out, int out_size, void* d_ws, size_t ws_size,
                              hipStream_t stream) {
  const float* x    = (const float*)d_in[0];
  const int*   apps = (const int*)d_in[1];
  const int*   esrc = (const int*)d_in[2];
  const int*   edst = (const int*)d_in[3];
  const float* emb  = (const float*)d_in[4];
  const float* gcw  = (const float*)d_in[5];
  const float* gcb  = (const float*)d_in[6];
  const float* W1   = (const float*)d_in[7];
  const float* b1   = (const float*)d_in[8];
  const float* W2   = (const float*)d_in[9];
  const float* b2   = (const float*)d_in[10];
  const float* W3   = (const float*)d_in[11];
  const float* b3   = (const float*)d_in[12];
  const float* W4   = (const float*)d_in[13];
  const float* b4   = (const float*)d_in[14];
  char* ws = (char*)d_ws;
  float* out = (float*)d_out;

  hipLaunchKernelGGL(p0a, dim3(1), dim3(256), 0, stream,
                     esrc, edst, emb, gcw, gcb, W1, b1, ws);
  hipLaunchKernelGGL(p0edge, dim3(32), dim3(256), 0, stream, esrc, edst, W1, ws);
  hipLaunchKernelGGL(p0pack, dim3(46), dim3(256), 0, stream, W1, W2, W3, ws);
  hipLaunchKernelGGL(fused_main, dim3(256), dim3(512), 0, stream,
                     x, apps, ws, b2, b3, W4, b4, out);
}